// Round 5
// baseline (2393.415 us; speedup 1.0000x reference)
//
#include <hip/hip_runtime.h>
#include <math.h>

typedef __attribute__((ext_vector_type(8))) short short8;
typedef __attribute__((ext_vector_type(4))) float float4v;

#define EPB 8192  // edges per block for hist/bin

__device__ __forceinline__ unsigned short f2bf(float f) {
  unsigned int u = __float_as_uint(f);
  unsigned int r = (u + 0x7fffu + ((u >> 16) & 1u)) >> 16;  // RNE
  return (unsigned short)r;
}

struct SetDesc {
  const int* src; const int* dst; const float* w;
  int2* pk;
  int E, shift, nb, cntBase, blkBase;
};
struct AllSets { SetDesc s[4]; };

// ---------------------------------------------------------------------------
// Weight conversion: W[K][128] fp32 -> frag-major bf16 layout.
// ---------------------------------------------------------------------------
__global__ __launch_bounds__(256) void conv_w_kernel(
    const float* __restrict__ W1a, const float* __restrict__ W1b,
    const float* __restrict__ W2a, const float* __restrict__ W2b,
    unsigned short* __restrict__ F1a, unsigned short* __restrict__ F1b,
    unsigned short* __restrict__ F2a, unsigned short* __restrict__ F2b) {
  int t = blockIdx.x * 256 + threadIdx.x;
  const float* W; unsigned short* F; int KB;
  if (t < 4096) { W = W1a; F = F1a; KB = 8; }
  else if (t < 6144) { W = W1b; F = F1b; KB = 4; t -= 4096; }
  else if (t < 10240) { W = W2a; F = F2a; KB = 8; t -= 6144; }
  else if (t < 12288) { W = W2b; F = F2b; KB = 4; t -= 10240; }
  else return;
  int lane = t & 63;
  int frag = t >> 6;
  int nt = frag / KB;
  int kb = frag - nt * KB;
  int k = kb * 32 + (lane >> 4) * 8;
  int n = nt * 16 + (lane & 15);
  unsigned short v[8];
  #pragma unroll
  for (int j = 0; j < 8; ++j) v[j] = f2bf(W[(long long)(k + j) * 128 + n]);
  unsigned short* o = F + ((long long)frag * 64 + lane) * 8;
  *reinterpret_cast<int4*>(o) = *reinterpret_cast<int4*>(v);
}

// ---------------------------------------------------------------------------
// MFMA GEMM: Y[N,128] = relu(X[N,K] @ W + bias). 4 waves/block, 16 rows/wave.
// ---------------------------------------------------------------------------
template <int K>
__global__ __launch_bounds__(256) void gemm_mfma_kernel(
    const float* __restrict__ X, const unsigned short* __restrict__ Wf,
    const float* __restrict__ bias, float* __restrict__ Y, int N) {
  constexpr int KB = K / 32;
  const int lane = threadIdx.x & 63;
  const int wave = threadIdx.x >> 6;
  const int m_base = blockIdx.x * 64 + wave * 16;

  int arow = m_base + (lane & 15);
  if (arow >= N) arow = N - 1;
  const float* aptr = X + (long long)arow * K + (lane >> 4) * 8;

  float4v acc[8];
  #pragma unroll
  for (int nt = 0; nt < 8; ++nt) acc[nt] = (float4v)(0.f);

  #pragma unroll
  for (int kb = 0; kb < KB; ++kb) {
    float4 a0 = *reinterpret_cast<const float4*>(aptr + kb * 32);
    float4 a1 = *reinterpret_cast<const float4*>(aptr + kb * 32 + 4);
    unsigned short u[8];
    u[0] = f2bf(a0.x); u[1] = f2bf(a0.y); u[2] = f2bf(a0.z); u[3] = f2bf(a0.w);
    u[4] = f2bf(a1.x); u[5] = f2bf(a1.y); u[6] = f2bf(a1.z); u[7] = f2bf(a1.w);
    short8 afrag = *reinterpret_cast<short8*>(u);
    #pragma unroll
    for (int nt = 0; nt < 8; ++nt) {
      short8 bfrag = *reinterpret_cast<const short8*>(
          Wf + ((long long)(nt * KB + kb) * 64 + lane) * 8);
      acc[nt] = __builtin_amdgcn_mfma_f32_16x16x32_bf16(afrag, bfrag, acc[nt], 0, 0, 0);
    }
  }

  const int col = lane & 15;
  const int rbase = (lane >> 4) * 4;
  #pragma unroll
  for (int nt = 0; nt < 8; ++nt) {
    int n = nt * 16 + col;
    float b = bias[n];
    #pragma unroll
    for (int r = 0; r < 4; ++r) {
      int grow = m_base + rbase + r;
      if (grow < N) Y[(long long)grow * 128 + n] = fmaxf(acc[nt][r] + b, 0.f);
    }
  }
}

// ---------------------------------------------------------------------------
// Bucket CSR build: LDS-aggregated bucket histogram, 1-block scan,
// block-aggregated binning.
// ---------------------------------------------------------------------------
__device__ __forceinline__ int decode_set(const AllSets& A, int b) {
  if (b < A.s[1].blkBase) return 0;
  if (b < A.s[2].blkBase) return 1;
  if (b < A.s[3].blkBase) return 2;
  return 3;
}

__global__ __launch_bounds__(256) void bucket_hist_kernel(AllSets A,
                                                          int* __restrict__ gcnt) {
  int b = blockIdx.x;
  SetDesc d = A.s[decode_set(A, b)];
  __shared__ int h[1024];
  int tid = threadIdx.x;
  for (int i = tid; i < 1024; i += 256) h[i] = 0;
  __syncthreads();
  int e0 = (b - d.blkBase) * EPB;
  int e1 = min(e0 + EPB, d.E);
  for (int e = e0 + tid; e < e1; e += 256)
    atomicAdd(&h[d.dst[e] >> d.shift], 1);
  __syncthreads();
  for (int i = tid; i < d.nb; i += 256)
    if (h[i]) atomicAdd(&gcnt[d.cntBase + i], h[i]);
}

// Single-block scan of up to 2048 bucket counts, with per-set carry resets.
__global__ __launch_bounds__(1024) void bucket_scan_kernel(
    const int* __restrict__ gcnt, int* __restrict__ cur,
    int* __restrict__ off11, int* __restrict__ off22,
    int* __restrict__ off01, int* __restrict__ off02,
    int nb11, int nb22, int nb01, int nb02) {
  __shared__ int val[2048];
  __shared__ int ssum[1024];
  __shared__ int exc[2049];
  int t = threadIdx.x;
  int b1 = nb11, b2 = nb11 + nb22, b3 = b2 + nb01, b4 = b3 + nb02;
  int i0 = 2 * t, i1 = 2 * t + 1;
  val[i0] = (i0 < b4) ? gcnt[i0] : 0;
  val[i1] = (i1 < b4) ? gcnt[i1] : 0;
  int pair = val[i0] + val[i1];
  ssum[t] = pair;
  __syncthreads();
  #pragma unroll
  for (int off = 1; off < 1024; off <<= 1) {
    int x = (t >= off) ? ssum[t - off] : 0;
    __syncthreads();
    ssum[t] += x;
    __syncthreads();
  }
  int e0 = ssum[t] - pair;
  exc[i0] = e0;
  exc[i1] = e0 + val[i0];
  if (t == 1023) exc[2048] = ssum[1023];
  __syncthreads();
  for (int i = t; i < b4; i += 1024) {
    int sS, base; int* optr;
    if (i < b1) { sS = 0; base = 0; optr = off11; }
    else if (i < b2) { sS = b1; base = b1; optr = off22; }
    else if (i < b3) { sS = b2; base = b2; optr = off01; }
    else { sS = b3; base = b3; optr = off02; }
    int v = exc[i] - exc[sS];
    optr[i - base] = v;
    cur[i] = v;
  }
  if (t == 0) {
    off11[nb11] = exc[b1] - exc[0];
    off22[nb22] = exc[b2] - exc[b1];
    off01[nb01] = exc[b3] - exc[b2];
    off02[nb02] = exc[b4] - exc[b3];
  }
}

__global__ __launch_bounds__(256) void bin_all_kernel(AllSets A,
                                                      int* __restrict__ cur) {
  int b = blockIdx.x;
  SetDesc d = A.s[decode_set(A, b)];
  __shared__ int hc[1024];
  __shared__ int hb[1024];
  int tid = threadIdx.x;
  for (int i = tid; i < 1024; i += 256) hc[i] = 0;
  __syncthreads();
  int e0 = (b - d.blkBase) * EPB;
  int e1 = min(e0 + EPB, d.E);
  for (int e = e0 + tid; e < e1; e += 256)
    atomicAdd(&hc[d.dst[e] >> d.shift], 1);
  __syncthreads();
  for (int i = tid; i < d.nb; i += 256) {
    int c = hc[i];
    if (c) hb[i] = atomicAdd(&cur[d.cntBase + i], c);
    hc[i] = 0;
  }
  __syncthreads();
  int mask = (1 << d.shift) - 1;
  for (int e = e0 + tid; e < e1; e += 256) {
    int dstv = d.dst[e];
    int bkt = dstv >> d.shift;
    int pos = atomicAdd(&hc[bkt], 1);
    int idx = hb[bkt] + pos;
    d.pk[idx] = make_int2(((dstv & mask) << 16) | d.src[e],
                          __float_as_int(d.w[e]));
  }
}

// ---------------------------------------------------------------------------
// Bucket pull for h11/h22: one block per 64-row bucket, LDS fp32 accumulate.
// ---------------------------------------------------------------------------
__global__ __launch_bounds__(256) void pull_h_kernel(
    const int* __restrict__ off1, const int2* __restrict__ pk1,
    const float* __restrict__ X1, float* __restrict__ Y1, int N1, int nbk1,
    const int* __restrict__ off2, const int2* __restrict__ pk2,
    const float* __restrict__ X2_, float* __restrict__ Y2, int N2) {
  int b = blockIdx.x;
  const int* off; const int2* pk; const float* X; float* Y; int N; int bkt;
  if (b < nbk1) { off = off1; pk = pk1; X = X1; Y = Y1; N = N1; bkt = b; }
  else { off = off2; pk = pk2; X = X2_; Y = Y2; N = N2; bkt = b - nbk1; }

  __shared__ float acc[64 * 128];  // 32 KB
  int tid = threadIdx.x;
  #pragma unroll
  for (int i = tid * 4; i < 8192; i += 1024)
    *reinterpret_cast<float4*>(&acc[i]) = make_float4(0.f, 0.f, 0.f, 0.f);
  __syncthreads();

  int beg = off[bkt], end = off[bkt + 1];
  int lane = tid & 63, wave = tid >> 6;
  const float2* X2 = (const float2*)X;
  for (int j = beg + wave; j < end; j += 4) {
    int2 rec = pk[j];
    int src = rec.x & 0xffff;
    int dl = rec.x >> 16;
    float wt = __int_as_float(rec.y);
    float2 v = X2[(long long)src * 64 + lane];
    float* ap = &acc[dl * 128 + lane * 2];
    atomicAdd(ap, wt * v.x);
    atomicAdd(ap + 1, wt * v.y);
  }
  __syncthreads();

  int r0 = bkt << 6;
  int nflt = min(64, N - r0) << 7;
  float* Yb = Y + ((long long)r0 << 7);
  for (int i = tid * 4; i < nflt; i += 1024)
    *reinterpret_cast<float4*>(Yb + i) = *reinterpret_cast<const float4*>(acc + i);
}

__device__ __forceinline__ float wave_sum64(float s) {
  #pragma unroll
  for (int off = 32; off; off >>= 1) s += __shfl_xor(s, off);
  return s;
}

// ---------------------------------------------------------------------------
// doc2: e01 buckets (32 rows), accumulate l2_1 & l1_1, l2norm, write cols 0..127
// ---------------------------------------------------------------------------
__global__ __launch_bounds__(256) void doc2_kernel(
    const int* __restrict__ off, const int2* __restrict__ pk,
    const float* __restrict__ Xa, const float* __restrict__ Xb,
    float* __restrict__ out, int N0) {
  int bkt = blockIdx.x;
  __shared__ float accA[32 * 128];
  __shared__ float accB[32 * 128];
  int tid = threadIdx.x;
  #pragma unroll
  for (int i = tid * 4; i < 4096; i += 1024) {
    *reinterpret_cast<float4*>(&accA[i]) = make_float4(0.f, 0.f, 0.f, 0.f);
    *reinterpret_cast<float4*>(&accB[i]) = make_float4(0.f, 0.f, 0.f, 0.f);
  }
  __syncthreads();

  int beg = off[bkt], end = off[bkt + 1];
  int lane = tid & 63, wave = tid >> 6;
  const float2* A2 = (const float2*)Xa;
  const float2* B2 = (const float2*)Xb;
  for (int j = beg + wave; j < end; j += 4) {
    int2 rec = pk[j];
    int src = rec.x & 0xffff;
    int dl = rec.x >> 16;
    float wt = __int_as_float(rec.y);
    float2 va = A2[(long long)src * 64 + lane];
    float2 vb = B2[(long long)src * 64 + lane];
    float* pa = &accA[dl * 128 + lane * 2];
    float* pb = &accB[dl * 128 + lane * 2];
    atomicAdd(pa, wt * va.x);
    atomicAdd(pa + 1, wt * va.y);
    atomicAdd(pb, wt * vb.x);
    atomicAdd(pb + 1, wt * vb.y);
  }
  __syncthreads();

  const long long DOC = (long long)N0 * 384;
  int r0 = bkt << 5;
  for (int rr = wave; rr < 32; rr += 4) {
    int row = r0 + rr;
    if (row >= N0) break;
    float2 a = ((float2*)&accA[rr * 128])[lane];
    float sa = wave_sum64(a.x * a.x + a.y * a.y);
    float inva = 1.0f / (sqrtf(sa) + 1e-9f);
    ((float2*)(out + (long long)row * 384))[lane] = make_float2(a.x * inva, a.y * inva);
    float2 bb = ((float2*)&accB[rr * 128])[lane];
    float sb = wave_sum64(bb.x * bb.x + bb.y * bb.y);
    float invb = 1.0f / (sqrtf(sb) + 1e-9f);
    ((float2*)(out + DOC + (long long)row * 384))[lane] = make_float2(bb.x * invb, bb.y * invb);
  }
}

// ---------------------------------------------------------------------------
// doc3: e02 buckets (32 rows), accumulate l2_2, l1_2, wem; l2norm over 256-dim
// concat; write cols 128..383 of doc and doc_svd.
// ---------------------------------------------------------------------------
__global__ __launch_bounds__(256) void doc3_kernel(
    const int* __restrict__ off, const int2* __restrict__ pk,
    const float* __restrict__ Xa, const float* __restrict__ Xb,
    const float* __restrict__ Xw, float* __restrict__ out, int N0) {
  int bkt = blockIdx.x;
  __shared__ float accA[32 * 128];
  __shared__ float accB[32 * 128];
  __shared__ float accW[32 * 128];
  int tid = threadIdx.x;
  #pragma unroll
  for (int i = tid * 4; i < 4096; i += 1024) {
    *reinterpret_cast<float4*>(&accA[i]) = make_float4(0.f, 0.f, 0.f, 0.f);
    *reinterpret_cast<float4*>(&accB[i]) = make_float4(0.f, 0.f, 0.f, 0.f);
    *reinterpret_cast<float4*>(&accW[i]) = make_float4(0.f, 0.f, 0.f, 0.f);
  }
  __syncthreads();

  int beg = off[bkt], end = off[bkt + 1];
  int lane = tid & 63, wave = tid >> 6;
  const float2* A2 = (const float2*)Xa;
  const float2* B2 = (const float2*)Xb;
  const float2* W2 = (const float2*)Xw;
  for (int j = beg + wave; j < end; j += 4) {
    int2 rec = pk[j];
    int src = rec.x & 0xffff;
    int dl = rec.x >> 16;
    float wt = __int_as_float(rec.y);
    float2 va = A2[(long long)src * 64 + lane];
    float2 vb = B2[(long long)src * 64 + lane];
    float2 vw = W2[(long long)src * 64 + lane];
    float* pa = &accA[dl * 128 + lane * 2];
    float* pb = &accB[dl * 128 + lane * 2];
    float* pw = &accW[dl * 128 + lane * 2];
    atomicAdd(pa, wt * va.x);
    atomicAdd(pa + 1, wt * va.y);
    atomicAdd(pb, wt * vb.x);
    atomicAdd(pb + 1, wt * vb.y);
    atomicAdd(pw, wt * vw.x);
    atomicAdd(pw + 1, wt * vw.y);
  }
  __syncthreads();

  const long long DOC = (long long)N0 * 384;
  int r0 = bkt << 5;
  for (int rr = wave; rr < 32; rr += 4) {
    int row = r0 + rr;
    if (row >= N0) break;
    float2 a = ((float2*)&accA[rr * 128])[lane];
    float2 w = ((float2*)&accW[rr * 128])[lane];
    float2 bb = ((float2*)&accB[rr * 128])[lane];
    float swp = w.x * w.x + w.y * w.y;
    float sa = wave_sum64(a.x * a.x + a.y * a.y + swp);
    float inva = 1.0f / (sqrtf(sa) + 1e-9f);
    float* o0 = out + (long long)row * 384 + 128;
    ((float2*)o0)[lane] = make_float2(a.x * inva, a.y * inva);
    ((float2*)(o0 + 128))[lane] = make_float2(w.x * inva, w.y * inva);
    float sb = wave_sum64(bb.x * bb.x + bb.y * bb.y + swp);
    float invb = 1.0f / (sqrtf(sb) + 1e-9f);
    float* o1 = out + DOC + (long long)row * 384 + 128;
    ((float2*)o1)[lane] = make_float2(bb.x * invb, bb.y * invb);
    ((float2*)(o1 + 128))[lane] = make_float2(w.x * invb, w.y * invb);
  }
}

// ---------------------------------------------------------------------------
extern "C" void kernel_launch(void* const* d_in, const int* in_sizes, int n_in,
                              void* d_out, int out_size, void* d_ws,
                              size_t ws_size, hipStream_t stream) {
  const float* x1  = (const float*)d_in[0];
  const float* x2  = (const float*)d_in[1];
  const float* wem = (const float*)d_in[2];
  const float* W1a = (const float*)d_in[3];
  const float* b1a = (const float*)d_in[4];
  const float* W1b = (const float*)d_in[5];
  const float* b1b = (const float*)d_in[6];
  const float* W2a = (const float*)d_in[7];
  const float* b2a = (const float*)d_in[8];
  const float* W2b = (const float*)d_in[9];
  const float* b2b = (const float*)d_in[10];
  const int*   e11s = (const int*)d_in[11];
  const int*   e11d = (const int*)d_in[12];
  const float* e11w = (const float*)d_in[13];
  const int*   e22s = (const int*)d_in[14];
  const int*   e22d = (const int*)d_in[15];
  const float* e22w = (const float*)d_in[16];
  const int*   e01s = (const int*)d_in[17];
  const int*   e01d = (const int*)d_in[18];
  const float* e01w = (const float*)d_in[19];
  const int*   e02s = (const int*)d_in[20];
  const int*   e02d = (const int*)d_in[21];
  const float* e02w = (const float*)d_in[22];

  const int N0 = 10000;
  const int N1 = in_sizes[0] / 256;
  const int N2 = in_sizes[1] / 256;
  const int E11 = in_sizes[11];
  const int E22 = in_sizes[14];
  const int E01 = in_sizes[17];
  const int E02 = in_sizes[20];

  float* out = (float*)d_out;

  // ---- workspace layout ----
  char* base = (char*)d_ws;
  auto alloc = [&](size_t bytes) -> void* {
    void* r = (void*)base;
    base += (bytes + 255) & ~(size_t)255;
    return r;
  };
  float* l1_1 = (float*)alloc((size_t)N1 * 128 * 4);
  float* l1_2 = (float*)alloc((size_t)N2 * 128 * 4);
  float* l2_1 = (float*)alloc((size_t)N1 * 128 * 4);
  float* l2_2 = (float*)alloc((size_t)N2 * 128 * 4);
  float* h11  = (float*)alloc((size_t)N1 * 128 * 4);
  float* h22  = (float*)alloc((size_t)N2 * 128 * 4);

  unsigned short* F1a = (unsigned short*)alloc(8 * 8 * 64 * 8 * 2);
  unsigned short* F1b = (unsigned short*)alloc(8 * 4 * 64 * 8 * 2);
  unsigned short* F2a = (unsigned short*)alloc(8 * 8 * 64 * 8 * 2);
  unsigned short* F2b = (unsigned short*)alloc(8 * 4 * 64 * 8 * 2);

  // bucket geometry
  const int nb11 = (N1 + 63) >> 6;   // 64-row buckets
  const int nb22 = (N2 + 63) >> 6;
  const int nb01 = (N0 + 31) >> 5;   // 32-row buckets
  const int nb02 = (N0 + 31) >> 5;
  const int TOT = nb11 + nb22 + nb01 + nb02;  // <= 2048

  int* gcnt = (int*)alloc(2048 * 4);
  int* cur  = (int*)alloc(2048 * 4);
  int* off11 = (int*)alloc((size_t)(nb11 + 1) * 4);
  int* off22 = (int*)alloc((size_t)(nb22 + 1) * 4);
  int* off01 = (int*)alloc((size_t)(nb01 + 1) * 4);
  int* off02 = (int*)alloc((size_t)(nb02 + 1) * 4);
  int2* pk11 = (int2*)alloc((size_t)E11 * 8);
  int2* pk22 = (int2*)alloc((size_t)E22 * 8);
  int2* pk01 = (int2*)alloc((size_t)E01 * 8);
  int2* pk02 = (int2*)alloc((size_t)E02 * 8);

  // block partition for hist/bin
  const int B11 = (E11 + EPB - 1) / EPB;
  const int B22 = (E22 + EPB - 1) / EPB;
  const int B01 = (E01 + EPB - 1) / EPB;
  const int B02 = (E02 + EPB - 1) / EPB;
  const int BT = B11 + B22 + B01 + B02;

  AllSets A;
  A.s[0] = {e11s, e11d, e11w, pk11, E11, 6, nb11, 0, 0};
  A.s[1] = {e22s, e22d, e22w, pk22, E22, 6, nb22, nb11, B11};
  A.s[2] = {e01s, e01d, e01w, pk01, E01, 5, nb01, nb11 + nb22, B11 + B22};
  A.s[3] = {e02s, e02d, e02w, pk02, E02, 5, nb02, nb11 + nb22 + nb01,
            B11 + B22 + B01};

  // ---- bucket CSR build ----
  hipMemsetAsync(gcnt, 0, 2048 * 4, stream);
  bucket_hist_kernel<<<BT, 256, 0, stream>>>(A, gcnt);
  bucket_scan_kernel<<<1, 1024, 0, stream>>>(gcnt, cur, off11, off22, off01,
                                             off02, nb11, nb22, nb01, nb02);
  bin_all_kernel<<<BT, 256, 0, stream>>>(A, cur);

  // ---- weight conversion + layer 1 GEMMs (bf16 MFMA) ----
  conv_w_kernel<<<48, 256, 0, stream>>>(W1a, W1b, W2a, W2b, F1a, F1b, F2a, F2b);
  gemm_mfma_kernel<256><<<(N1 + 63) / 64, 256, 0, stream>>>(x1, F1a, b1a, l1_1, N1);
  gemm_mfma_kernel<256><<<(N2 + 63) / 64, 256, 0, stream>>>(x2, F2a, b2a, l1_2, N2);

  // ---- layer 2: bucket pull then GEMM ----
  pull_h_kernel<<<nb11 + nb22, 256, 0, stream>>>(off11, pk11, l1_1, h11, N1, nb11,
                                                 off22, pk22, l1_2, h22, N2);
  gemm_mfma_kernel<128><<<(N1 + 63) / 64, 256, 0, stream>>>(h11, F1b, b1b, l2_1, N1);
  gemm_mfma_kernel<128><<<(N2 + 63) / 64, 256, 0, stream>>>(h22, F2b, b2b, l2_2, N2);

  // ---- doc aggregation + l2norm + concat (fused) ----
  doc2_kernel<<<nb01, 256, 0, stream>>>(off01, pk01, l2_1, l1_1, out, N0);
  doc3_kernel<<<nb02, 256, 0, stream>>>(off02, pk02, l2_2, l1_2, wem, out, N0);
}

// Round 6
// 547.239 us; speedup vs baseline: 4.3736x; 4.3736x over previous
//
#include <hip/hip_runtime.h>
#include <math.h>

typedef __attribute__((ext_vector_type(8))) short short8;
typedef __attribute__((ext_vector_type(4))) float float4v;

#define EPB 8192       // edges per block for bin
#define SCHUNK 4096    // row-scan chunk
#define SORT_CAP 2560  // records per bucket capacity (lambda~1024, 48 sigma)

__device__ __forceinline__ unsigned short f2bf(float f) {
  unsigned int u = __float_as_uint(f);
  unsigned int r = (u + 0x7fffu + ((u >> 16) & 1u)) >> 16;  // RNE
  return (unsigned short)r;
}
__device__ __forceinline__ float bf2f(unsigned u16) {
  return __uint_as_float(u16 << 16);
}

struct SetFull {
  const int* src; const int* dst; const float* w;
  const int* offs;   // row offsets (N+1)
  int2* pkt;         // bucket-binned records
  int2* pkf;         // row-sorted records
  int E, N, shift, nb, cntBase, blkBase;
};
struct All4 { SetFull s[4]; };

// ---------------------------------------------------------------------------
// Weight conversion: W[K][128] fp32 -> frag-major bf16.
// ---------------------------------------------------------------------------
__global__ __launch_bounds__(256) void conv_w_kernel(
    const float* __restrict__ W1a, const float* __restrict__ W1b,
    const float* __restrict__ W2a, const float* __restrict__ W2b,
    unsigned short* __restrict__ F1a, unsigned short* __restrict__ F1b,
    unsigned short* __restrict__ F2a, unsigned short* __restrict__ F2b) {
  int t = blockIdx.x * 256 + threadIdx.x;
  const float* W; unsigned short* F; int KB;
  if (t < 4096) { W = W1a; F = F1a; KB = 8; }
  else if (t < 6144) { W = W1b; F = F1b; KB = 4; t -= 4096; }
  else if (t < 10240) { W = W2a; F = F2a; KB = 8; t -= 6144; }
  else if (t < 12288) { W = W2b; F = F2b; KB = 4; t -= 10240; }
  else return;
  int lane = t & 63;
  int frag = t >> 6;
  int nt = frag / KB;
  int kb = frag - nt * KB;
  int k = kb * 32 + (lane >> 4) * 8;
  int n = nt * 16 + (lane & 15);
  unsigned short v[8];
  #pragma unroll
  for (int j = 0; j < 8; ++j) v[j] = f2bf(W[(long long)(k + j) * 128 + n]);
  unsigned short* o = F + ((long long)frag * 64 + lane) * 8;
  *reinterpret_cast<int4*>(o) = *reinterpret_cast<int4*>(v);
}

// fp32 -> packed bf16 pairs (for word_emb)
__global__ __launch_bounds__(256) void conv_bf16_kernel(
    const float* __restrict__ in, unsigned* __restrict__ out, int npairs) {
  int t = blockIdx.x * 256 + threadIdx.x;
  if (t >= npairs) return;
  float2 v = reinterpret_cast<const float2*>(in)[t];
  out[t] = (unsigned)f2bf(v.x) | ((unsigned)f2bf(v.y) << 16);
}

// ---------------------------------------------------------------------------
// MFMA GEMM, fp32 A (layer 1, K=256): Y bf16 = relu(X@W+b)
// ---------------------------------------------------------------------------
template <int K>
__global__ __launch_bounds__(256) void gemm_mfma_f32a(
    const float* __restrict__ X, const unsigned short* __restrict__ Wf,
    const float* __restrict__ bias, unsigned short* __restrict__ Y, int N) {
  constexpr int KB = K / 32;
  const int lane = threadIdx.x & 63;
  const int wave = threadIdx.x >> 6;
  const int m_base = blockIdx.x * 64 + wave * 16;

  int arow = m_base + (lane & 15);
  if (arow >= N) arow = N - 1;
  const float* aptr = X + (long long)arow * K + (lane >> 4) * 8;

  float4v acc[8];
  #pragma unroll
  for (int nt = 0; nt < 8; ++nt) acc[nt] = (float4v)(0.f);

  #pragma unroll
  for (int kb = 0; kb < KB; ++kb) {
    float4 a0 = *reinterpret_cast<const float4*>(aptr + kb * 32);
    float4 a1 = *reinterpret_cast<const float4*>(aptr + kb * 32 + 4);
    unsigned short u[8];
    u[0] = f2bf(a0.x); u[1] = f2bf(a0.y); u[2] = f2bf(a0.z); u[3] = f2bf(a0.w);
    u[4] = f2bf(a1.x); u[5] = f2bf(a1.y); u[6] = f2bf(a1.z); u[7] = f2bf(a1.w);
    short8 afrag = *reinterpret_cast<short8*>(u);
    #pragma unroll
    for (int nt = 0; nt < 8; ++nt) {
      short8 bfrag = *reinterpret_cast<const short8*>(
          Wf + ((long long)(nt * KB + kb) * 64 + lane) * 8);
      acc[nt] = __builtin_amdgcn_mfma_f32_16x16x32_bf16(afrag, bfrag, acc[nt], 0, 0, 0);
    }
  }

  const int col = lane & 15;
  const int rbase = (lane >> 4) * 4;
  #pragma unroll
  for (int nt = 0; nt < 8; ++nt) {
    int n = nt * 16 + col;
    float b = bias[n];
    #pragma unroll
    for (int r = 0; r < 4; ++r) {
      int grow = m_base + rbase + r;
      if (grow < N) Y[(long long)grow * 128 + n] = f2bf(fmaxf(acc[nt][r] + b, 0.f));
    }
  }
}

// ---------------------------------------------------------------------------
// MFMA GEMM, bf16 A (layer 2, K=128): Y bf16 = relu(X@W+b)
// ---------------------------------------------------------------------------
template <int K>
__global__ __launch_bounds__(256) void gemm_mfma_bf16a(
    const unsigned short* __restrict__ X, const unsigned short* __restrict__ Wf,
    const float* __restrict__ bias, unsigned short* __restrict__ Y, int N) {
  constexpr int KB = K / 32;
  const int lane = threadIdx.x & 63;
  const int wave = threadIdx.x >> 6;
  const int m_base = blockIdx.x * 64 + wave * 16;

  int arow = m_base + (lane & 15);
  if (arow >= N) arow = N - 1;
  const unsigned short* aptr = X + (long long)arow * K + (lane >> 4) * 8;

  float4v acc[8];
  #pragma unroll
  for (int nt = 0; nt < 8; ++nt) acc[nt] = (float4v)(0.f);

  #pragma unroll
  for (int kb = 0; kb < KB; ++kb) {
    short8 afrag = *reinterpret_cast<const short8*>(aptr + kb * 32);
    #pragma unroll
    for (int nt = 0; nt < 8; ++nt) {
      short8 bfrag = *reinterpret_cast<const short8*>(
          Wf + ((long long)(nt * KB + kb) * 64 + lane) * 8);
      acc[nt] = __builtin_amdgcn_mfma_f32_16x16x32_bf16(afrag, bfrag, acc[nt], 0, 0, 0);
    }
  }

  const int col = lane & 15;
  const int rbase = (lane >> 4) * 4;
  #pragma unroll
  for (int nt = 0; nt < 8; ++nt) {
    int n = nt * 16 + col;
    float b = bias[n];
    #pragma unroll
    for (int r = 0; r < 4; ++r) {
      int grow = m_base + rbase + r;
      if (grow < N) Y[(long long)grow * 128 + n] = f2bf(fmaxf(acc[nt][r] + b, 0.f));
    }
  }
}

// ---------------------------------------------------------------------------
// Row-level histogram (global atomics) + 3-phase scan -> row offsets.
// ---------------------------------------------------------------------------
__global__ __launch_bounds__(256) void hist_all_kernel(
    const int* __restrict__ d11, int E11, int* __restrict__ c11,
    const int* __restrict__ d22, int E22, int* __restrict__ c22,
    const int* __restrict__ d01, int E01, int* __restrict__ c01,
    const int* __restrict__ d02, int E02, int* __restrict__ c02) {
  int t = blockIdx.x * 256 + threadIdx.x;
  if (t < E11) { atomicAdd(&c11[d11[t]], 1); return; }
  t -= E11;
  if (t < E22) { atomicAdd(&c22[d22[t]], 1); return; }
  t -= E22;
  if (t < E01) { atomicAdd(&c01[d01[t]], 1); return; }
  t -= E01;
  if (t < E02) { atomicAdd(&c02[d02[t]], 1); }
}

__global__ __launch_bounds__(256) void scan_local_kernel(
    const int* __restrict__ c11, int* __restrict__ o11, int n11,
    const int* __restrict__ c22, int* __restrict__ o22, int n22,
    const int* __restrict__ c01, int* __restrict__ o01, int n01,
    const int* __restrict__ c02, int* __restrict__ o02, int n02,
    int nc11, int nc22, int nc01, int* __restrict__ chunkSums) {
  int b = blockIdx.x;
  const int* c; int* o; int n; int chunk;
  if (b < nc11) { c = c11; o = o11; n = n11; chunk = b; }
  else if (b < nc11 + nc22) { c = c22; o = o22; n = n22; chunk = b - nc11; }
  else if (b < nc11 + nc22 + nc01) { c = c01; o = o01; n = n01; chunk = b - nc11 - nc22; }
  else { c = c02; o = o02; n = n02; chunk = b - nc11 - nc22 - nc01; }
  int tid = threadIdx.x;
  int i0 = chunk * SCHUNK + tid * 16;
  int loc[16];
  int s = 0;
  #pragma unroll
  for (int k = 0; k < 16; ++k) {
    int i = i0 + k;
    int x = (i < n) ? c[i] : 0;
    loc[k] = s;
    s += x;
  }
  __shared__ int sh[256];
  sh[tid] = s;
  __syncthreads();
  #pragma unroll
  for (int off = 1; off < 256; off <<= 1) {
    int t = (tid >= off) ? sh[tid - off] : 0;
    __syncthreads();
    sh[tid] += t;
    __syncthreads();
  }
  int excl = sh[tid] - s;
  #pragma unroll
  for (int k = 0; k < 16; ++k) {
    int i = i0 + k;
    if (i < n) o[i] = excl + loc[k];
  }
  if (tid == 255) chunkSums[b] = sh[255];
}

__global__ __launch_bounds__(64) void scan_sums_kernel(
    const int* __restrict__ chunkSums, int* __restrict__ chunkOffs,
    int nc11, int nc22, int nc01, int tc) {
  __shared__ int sh[64];
  int tid = threadIdx.x;
  if (tid < tc) sh[tid] = chunkSums[tid];
  __syncthreads();
  if (tid == 0) {
    int carry = 0;
    for (int b = 0; b < tc; ++b) {
      if (b == 0 || b == nc11 || b == nc11 + nc22 || b == nc11 + nc22 + nc01)
        carry = 0;
      chunkOffs[b] = carry;
      carry += sh[b];
    }
  }
}

__global__ __launch_bounds__(256) void scan_add_kernel(
    int* __restrict__ o11, int n11, int* __restrict__ o22, int n22,
    int* __restrict__ o01, int n01, int* __restrict__ o02, int n02,
    int nc11, int nc22, int nc01, const int* __restrict__ chunkOffs) {
  int b = blockIdx.x;
  int* o; int n; int chunk;
  if (b < nc11) { o = o11; n = n11; chunk = b; }
  else if (b < nc11 + nc22) { o = o22; n = n22; chunk = b - nc11; }
  else if (b < nc11 + nc22 + nc01) { o = o01; n = n01; chunk = b - nc11 - nc22; }
  else { o = o02; n = n02; chunk = b - nc11 - nc22 - nc01; }
  int add = chunkOffs[b];
  int tid = threadIdx.x;
  int i0 = chunk * SCHUNK + tid * 16;
  #pragma unroll
  for (int k = 0; k < 16; ++k) {
    int i = i0 + k;
    if (i < n) o[i] += add;
  }
}

// ---------------------------------------------------------------------------
// Bucket cursor init: cur[bucket] = row_offs[firstRow(bucket)]
// ---------------------------------------------------------------------------
__global__ __launch_bounds__(256) void bucket_cur_init(All4 A, int* __restrict__ cur,
                                                       int totb) {
  int i = blockIdx.x * 256 + threadIdx.x;
  if (i >= totb) return;
  int si = 3;
  if (i < A.s[1].cntBase) si = 0;
  else if (i < A.s[2].cntBase) si = 1;
  else if (i < A.s[3].cntBase) si = 2;
  const SetFull& d = A.s[si];
  int j = i - d.cntBase;
  cur[i] = d.offs[j << d.shift];
}

// ---------------------------------------------------------------------------
// Bucket binning: LDS hist -> block-aggregated reservation -> packed write.
// ---------------------------------------------------------------------------
__global__ __launch_bounds__(256) void bin_all_kernel(All4 A, int* __restrict__ cur) {
  int b = blockIdx.x;
  int si = 3;
  if (b < A.s[1].blkBase) si = 0;
  else if (b < A.s[2].blkBase) si = 1;
  else if (b < A.s[3].blkBase) si = 2;
  SetFull d = A.s[si];
  __shared__ int hc[1024];
  __shared__ int hb[1024];
  int tid = threadIdx.x;
  for (int i = tid; i < 1024; i += 256) hc[i] = 0;
  __syncthreads();
  int e0 = (b - d.blkBase) * EPB;
  int e1 = min(e0 + EPB, d.E);
  for (int e = e0 + tid; e < e1; e += 256)
    atomicAdd(&hc[d.dst[e] >> d.shift], 1);
  __syncthreads();
  for (int i = tid; i < d.nb; i += 256) {
    int c = hc[i];
    if (c) hb[i] = atomicAdd(&cur[d.cntBase + i], c);
    hc[i] = 0;
  }
  __syncthreads();
  int mask = (1 << d.shift) - 1;
  for (int e = e0 + tid; e < e1; e += 256) {
    int dstv = d.dst[e];
    int bkt = dstv >> d.shift;
    int pos = atomicAdd(&hc[bkt], 1);
    d.pkt[hb[bkt] + pos] = make_int2(((dstv & mask) << 16) | d.src[e],
                                     __float_as_int(d.w[e]));
  }
}

// ---------------------------------------------------------------------------
// Per-bucket LDS counting sort: pkt (bucket-binned) -> pkf (row-ordered).
// ---------------------------------------------------------------------------
__global__ __launch_bounds__(256) void sort_kernel(All4 A) {
  int b = blockIdx.x;
  int si = 3;
  if (b < A.s[1].cntBase) si = 0;
  else if (b < A.s[2].cntBase) si = 1;
  else if (b < A.s[3].cntBase) si = 2;
  SetFull d = A.s[si];
  int j = b - d.cntBase;
  int R = 1 << d.shift;
  int rb = j << d.shift;
  int rend = min(rb + R, d.N);
  __shared__ int rowCur[64];
  __shared__ int2 buf[SORT_CAP];
  int tid = threadIdx.x;
  int bucketStart = d.offs[rb];
  if (tid < rend - rb) rowCur[tid] = d.offs[rb + tid] - bucketStart;
  __syncthreads();
  int cnt = d.offs[rend] - bucketStart;
  if (cnt > SORT_CAP) cnt = SORT_CAP;  // statistically unreachable
  for (int t = tid; t < cnt; t += 256) {
    int2 rec = d.pkt[bucketStart + t];
    int dl = ((unsigned)rec.x) >> 16;
    int pos = atomicAdd(&rowCur[dl], 1);
    buf[pos] = rec;
  }
  __syncthreads();
  for (int t = tid; t < cnt; t += 256) d.pkf[bucketStart + t] = buf[t];
}

// ---------------------------------------------------------------------------
// Per-row register pull (bf16 gather), h11+h22 fused; writes bf16.
// ---------------------------------------------------------------------------
__global__ __launch_bounds__(256) void pull_h_kernel(
    const int* __restrict__ off1, const int2* __restrict__ pk1,
    const unsigned* __restrict__ X1, unsigned* __restrict__ Y1, int N1,
    const int* __restrict__ off2, const int2* __restrict__ pk2,
    const unsigned* __restrict__ X2, unsigned* __restrict__ Y2, int N2) {
  int row = blockIdx.x * 4 + (threadIdx.x >> 6);
  int lane = threadIdx.x & 63;
  const int* off; const int2* pk; const unsigned* X; unsigned* Y;
  if (row < N1) { off = off1; pk = pk1; X = X1; Y = Y1; }
  else {
    row -= N1;
    if (row >= N2) return;
    off = off2; pk = pk2; X = X2; Y = Y2;
  }
  int beg = off[row], end = off[row + 1];
  float ax = 0.f, ay = 0.f;
  int j = beg;
  for (; j + 1 < end; j += 2) {
    int2 p0 = pk[j];
    int2 p1 = pk[j + 1];
    unsigned v0 = X[((p0.x & 0xffff) << 6) + lane];
    unsigned v1 = X[((p1.x & 0xffff) << 6) + lane];
    float w0 = __int_as_float(p0.y);
    float w1 = __int_as_float(p1.y);
    ax += w0 * bf2f(v0 & 0xffff) + w1 * bf2f(v1 & 0xffff);
    ay += w0 * bf2f(v0 >> 16) + w1 * bf2f(v1 >> 16);
  }
  if (j < end) {
    int2 p0 = pk[j];
    unsigned v0 = X[((p0.x & 0xffff) << 6) + lane];
    float w0 = __int_as_float(p0.y);
    ax += w0 * bf2f(v0 & 0xffff);
    ay += w0 * bf2f(v0 >> 16);
  }
  Y[(row << 6) + lane] = (unsigned)f2bf(ax) | ((unsigned)f2bf(ay) << 16);
}

__device__ __forceinline__ float wave_sum64(float s) {
  #pragma unroll
  for (int off = 32; off; off >>= 1) s += __shfl_xor(s, off);
  return s;
}

// doc2: e01 rows; acc l2_1 & l1_1 (bf16); l2norm; out cols [0,128)
__global__ __launch_bounds__(256) void doc2_kernel(
    const int* __restrict__ offs, const int2* __restrict__ pk,
    const unsigned* __restrict__ Xa, const unsigned* __restrict__ Xb,
    float* __restrict__ out, int N0) {
  int row = blockIdx.x * 4 + (threadIdx.x >> 6);
  int lane = threadIdx.x & 63;
  if (row >= N0) return;
  int beg = offs[row], end = offs[row + 1];
  float axx = 0.f, axy = 0.f, bxx = 0.f, bxy = 0.f;
  for (int j = beg; j < end; ++j) {
    int2 p = pk[j];
    int s = (p.x & 0xffff) << 6;
    float w = __int_as_float(p.y);
    unsigned va = Xa[s + lane];
    unsigned vb = Xb[s + lane];
    axx += w * bf2f(va & 0xffff);
    axy += w * bf2f(va >> 16);
    bxx += w * bf2f(vb & 0xffff);
    bxy += w * bf2f(vb >> 16);
  }
  const long long DOC = (long long)N0 * 384;
  float sa = wave_sum64(axx * axx + axy * axy);
  float inva = 1.0f / (sqrtf(sa) + 1e-9f);
  ((float2*)(out + (long long)row * 384))[lane] = make_float2(axx * inva, axy * inva);
  float sb = wave_sum64(bxx * bxx + bxy * bxy);
  float invb = 1.0f / (sqrtf(sb) + 1e-9f);
  ((float2*)(out + DOC + (long long)row * 384))[lane] = make_float2(bxx * invb, bxy * invb);
}

// doc3: e02 rows; acc l2_2, l1_2, wem (bf16); l2norm 256-dim; out cols [128,384)
__global__ __launch_bounds__(256) void doc3_kernel(
    const int* __restrict__ offs, const int2* __restrict__ pk,
    const unsigned* __restrict__ Xa, const unsigned* __restrict__ Xb,
    const unsigned* __restrict__ Xw, float* __restrict__ out, int N0) {
  int row = blockIdx.x * 4 + (threadIdx.x >> 6);
  int lane = threadIdx.x & 63;
  if (row >= N0) return;
  int beg = offs[row], end = offs[row + 1];
  float axx = 0.f, axy = 0.f, bxx = 0.f, bxy = 0.f, wxx = 0.f, wxy = 0.f;
  for (int j = beg; j < end; ++j) {
    int2 p = pk[j];
    int s = (p.x & 0xffff) << 6;
    float w = __int_as_float(p.y);
    unsigned va = Xa[s + lane];
    unsigned vb = Xb[s + lane];
    unsigned vw = Xw[s + lane];
    axx += w * bf2f(va & 0xffff); axy += w * bf2f(va >> 16);
    bxx += w * bf2f(vb & 0xffff); bxy += w * bf2f(vb >> 16);
    wxx += w * bf2f(vw & 0xffff); wxy += w * bf2f(vw >> 16);
  }
  const long long DOC = (long long)N0 * 384;
  float swp = wxx * wxx + wxy * wxy;
  float sa = wave_sum64(axx * axx + axy * axy + swp);
  float inva = 1.0f / (sqrtf(sa) + 1e-9f);
  float* o0 = out + (long long)row * 384 + 128;
  ((float2*)o0)[lane] = make_float2(axx * inva, axy * inva);
  ((float2*)(o0 + 128))[lane] = make_float2(wxx * inva, wxy * inva);
  float sb = wave_sum64(bxx * bxx + bxy * bxy + swp);
  float invb = 1.0f / (sqrtf(sb) + 1e-9f);
  float* o1 = out + DOC + (long long)row * 384 + 128;
  ((float2*)o1)[lane] = make_float2(bxx * invb, bxy * invb);
  ((float2*)(o1 + 128))[lane] = make_float2(wxx * invb, wxy * invb);
}

// ---------------------------------------------------------------------------
extern "C" void kernel_launch(void* const* d_in, const int* in_sizes, int n_in,
                              void* d_out, int out_size, void* d_ws,
                              size_t ws_size, hipStream_t stream) {
  const float* x1  = (const float*)d_in[0];
  const float* x2  = (const float*)d_in[1];
  const float* wem = (const float*)d_in[2];
  const float* W1a = (const float*)d_in[3];
  const float* b1a = (const float*)d_in[4];
  const float* W1b = (const float*)d_in[5];
  const float* b1b = (const float*)d_in[6];
  const float* W2a = (const float*)d_in[7];
  const float* b2a = (const float*)d_in[8];
  const float* W2b = (const float*)d_in[9];
  const float* b2b = (const float*)d_in[10];
  const int*   e11s = (const int*)d_in[11];
  const int*   e11d = (const int*)d_in[12];
  const float* e11w = (const float*)d_in[13];
  const int*   e22s = (const int*)d_in[14];
  const int*   e22d = (const int*)d_in[15];
  const float* e22w = (const float*)d_in[16];
  const int*   e01s = (const int*)d_in[17];
  const int*   e01d = (const int*)d_in[18];
  const float* e01w = (const float*)d_in[19];
  const int*   e02s = (const int*)d_in[20];
  const int*   e02d = (const int*)d_in[21];
  const float* e02w = (const float*)d_in[22];

  const int N0 = 10000;
  const int N1 = in_sizes[0] / 256;
  const int N2 = in_sizes[1] / 256;
  const int E11 = in_sizes[11];
  const int E22 = in_sizes[14];
  const int E01 = in_sizes[17];
  const int E02 = in_sizes[20];

  float* out = (float*)d_out;

  // ---- workspace ----
  char* base = (char*)d_ws;
  auto alloc = [&](size_t bytes) -> void* {
    void* r = (void*)base;
    base += (bytes + 255) & ~(size_t)255;
    return r;
  };
  // bf16 feature matrices (packed as unsigned pairs, 64 dwords/row)
  unsigned* l1_1 = (unsigned*)alloc((size_t)N1 * 64 * 4);
  unsigned* l1_2 = (unsigned*)alloc((size_t)N2 * 64 * 4);
  unsigned* l2_1 = (unsigned*)alloc((size_t)N1 * 64 * 4);
  unsigned* l2_2 = (unsigned*)alloc((size_t)N2 * 64 * 4);
  unsigned* h11  = (unsigned*)alloc((size_t)N1 * 64 * 4);
  unsigned* h22  = (unsigned*)alloc((size_t)N2 * 64 * 4);
  unsigned* wemb = (unsigned*)alloc((size_t)N2 * 64 * 4);

  unsigned short* F1a = (unsigned short*)alloc(8 * 8 * 64 * 8 * 2);
  unsigned short* F1b = (unsigned short*)alloc(8 * 4 * 64 * 8 * 2);
  unsigned short* F2a = (unsigned short*)alloc(8 * 8 * 64 * 8 * 2);
  unsigned short* F2b = (unsigned short*)alloc(8 * 4 * 64 * 8 * 2);

  const int n11 = N1 + 1, n22 = N2 + 1, n01 = N0 + 1, n02 = N0 + 1;
  const int P1 = (n11 + 63) & ~63;
  const int P2 = (n22 + 63) & ~63;
  const int P0 = (n01 + 63) & ~63;
  int* cnt_all = (int*)alloc((size_t)(P1 + P2 + P0 + P0) * 4);
  int* cnt11 = cnt_all;
  int* cnt22 = cnt_all + P1;
  int* cnt01 = cnt_all + P1 + P2;
  int* cnt02 = cnt_all + P1 + P2 + P0;
  int* off11 = (int*)alloc((size_t)P1 * 4);
  int* off22 = (int*)alloc((size_t)P2 * 4);
  int* off01 = (int*)alloc((size_t)P0 * 4);
  int* off02 = (int*)alloc((size_t)P0 * 4);
  int2* pkt11 = (int2*)alloc((size_t)E11 * 8);
  int2* pkt22 = (int2*)alloc((size_t)E22 * 8);
  int2* pkt01 = (int2*)alloc((size_t)E01 * 8);
  int2* pkt02 = (int2*)alloc((size_t)E02 * 8);
  int2* pkf11 = (int2*)alloc((size_t)E11 * 8);
  int2* pkf22 = (int2*)alloc((size_t)E22 * 8);
  int2* pkf01 = (int2*)alloc((size_t)E01 * 8);
  int2* pkf02 = (int2*)alloc((size_t)E02 * 8);
  int* bcur = (int*)alloc(2048 * 4);
  int* chunkSums = (int*)alloc(64 * 4);
  int* chunkOffs = (int*)alloc(64 * 4);

  // geometry
  const int nb11 = (N1 + 63) >> 6, nb22 = (N2 + 63) >> 6;
  const int nb01 = (N0 + 31) >> 5, nb02 = (N0 + 31) >> 5;
  const int TOTB = nb11 + nb22 + nb01 + nb02;
  const int B11 = (E11 + EPB - 1) / EPB, B22 = (E22 + EPB - 1) / EPB;
  const int B01 = (E01 + EPB - 1) / EPB, B02 = (E02 + EPB - 1) / EPB;
  const int BT = B11 + B22 + B01 + B02;
  const int Etot = E11 + E22 + E01 + E02;
  const int nc11 = (n11 + SCHUNK - 1) / SCHUNK;
  const int nc22 = (n22 + SCHUNK - 1) / SCHUNK;
  const int nc01 = (n01 + SCHUNK - 1) / SCHUNK;
  const int nc02 = (n02 + SCHUNK - 1) / SCHUNK;
  const int TC = nc11 + nc22 + nc01 + nc02;

  All4 A;
  A.s[0] = {e11s, e11d, e11w, off11, pkt11, pkf11, E11, N1, 6, nb11, 0, 0};
  A.s[1] = {e22s, e22d, e22w, off22, pkt22, pkf22, E22, N2, 6, nb22, nb11, B11};
  A.s[2] = {e01s, e01d, e01w, off01, pkt01, pkf01, E01, N0, 5, nb01,
            nb11 + nb22, B11 + B22};
  A.s[3] = {e02s, e02d, e02w, off02, pkt02, pkf02, E02, N0, 5, nb02,
            nb11 + nb22 + nb01, B11 + B22 + B01};

  // ---- row CSR offsets ----
  hipMemsetAsync(cnt_all, 0, (size_t)(P1 + P2 + P0 + P0) * 4, stream);
  hist_all_kernel<<<(Etot + 255) / 256, 256, 0, stream>>>(
      e11d, E11, cnt11, e22d, E22, cnt22, e01d, E01, cnt01, e02d, E02, cnt02);
  scan_local_kernel<<<TC, 256, 0, stream>>>(
      cnt11, off11, n11, cnt22, off22, n22, cnt01, off01, n01,
      cnt02, off02, n02, nc11, nc22, nc01, chunkSums);
  scan_sums_kernel<<<1, 64, 0, stream>>>(chunkSums, chunkOffs, nc11, nc22, nc01, TC);
  scan_add_kernel<<<TC, 256, 0, stream>>>(
      off11, n11, off22, n22, off01, n01, off02, n02, nc11, nc22, nc01, chunkOffs);

  // ---- bucket bin + per-bucket row sort ----
  bucket_cur_init<<<(TOTB + 255) / 256, 256, 0, stream>>>(A, bcur, TOTB);
  bin_all_kernel<<<BT, 256, 0, stream>>>(A, bcur);
  sort_kernel<<<TOTB, 256, 0, stream>>>(A);

  // ---- weight + wem conversion, layer-1 GEMMs ----
  conv_w_kernel<<<48, 256, 0, stream>>>(W1a, W1b, W2a, W2b, F1a, F1b, F2a, F2b);
  conv_bf16_kernel<<<(N2 * 64 + 255) / 256, 256, 0, stream>>>(wem, wemb, N2 * 64);
  gemm_mfma_f32a<256><<<(N1 + 63) / 64, 256, 0, stream>>>(x1, F1a, b1a,
                                                          (unsigned short*)l1_1, N1);
  gemm_mfma_f32a<256><<<(N2 + 63) / 64, 256, 0, stream>>>(x2, F2a, b2a,
                                                          (unsigned short*)l1_2, N2);

  // ---- layer 2: per-row pull then GEMM ----
  pull_h_kernel<<<(N1 + N2 + 3) / 4, 256, 0, stream>>>(
      off11, pkf11, l1_1, h11, N1, off22, pkf22, l1_2, h22, N2);
  gemm_mfma_bf16a<128><<<(N1 + 63) / 64, 256, 0, stream>>>(
      (const unsigned short*)h11, F1b, b1b, (unsigned short*)l2_1, N1);
  gemm_mfma_bf16a<128><<<(N2 + 63) / 64, 256, 0, stream>>>(
      (const unsigned short*)h22, F2b, b2b, (unsigned short*)l2_2, N2);

  // ---- doc aggregation + l2norm + concat ----
  doc2_kernel<<<(N0 + 3) / 4, 256, 0, stream>>>(off01, pkf01, l2_1, l1_1, out, N0);
  doc3_kernel<<<(N0 + 3) / 4, 256, 0, stream>>>(off02, pkf02, l2_2, l1_2, wemb, out, N0);
}

// Round 7
// 502.085 us; speedup vs baseline: 4.7670x; 1.0899x over previous
//
#include <hip/hip_runtime.h>
#include <math.h>

typedef __attribute__((ext_vector_type(8))) short short8;
typedef __attribute__((ext_vector_type(4))) float float4v;

#define EPB 8192       // edges per block for bin
#define SCHUNK 4096    // row-scan chunk
#define SORT_CAP 2560  // records per bucket capacity (lambda~1024, 48 sigma)

__device__ __forceinline__ unsigned short f2bf(float f) {
  unsigned int u = __float_as_uint(f);
  unsigned int r = (u + 0x7fffu + ((u >> 16) & 1u)) >> 16;  // RNE
  return (unsigned short)r;
}
__device__ __forceinline__ float bf2f(unsigned u16) {
  return __uint_as_float(u16 << 16);
}

struct SetFull {
  const int* src; const int* dst; const float* w;
  const int* offs;   // row offsets (N+1)
  int2* pkt;         // bucket-binned records
  int2* pkf;         // row-sorted records
  int E, N, shift, nb, cntBase, blkBase;
};
struct All4 { SetFull s[4]; };

// ---------------------------------------------------------------------------
// Weight conversion: W[K][128] fp32 -> frag-major bf16.
// ---------------------------------------------------------------------------
__global__ __launch_bounds__(256) void conv_w_kernel(
    const float* __restrict__ W1a, const float* __restrict__ W1b,
    const float* __restrict__ W2a, const float* __restrict__ W2b,
    unsigned short* __restrict__ F1a, unsigned short* __restrict__ F1b,
    unsigned short* __restrict__ F2a, unsigned short* __restrict__ F2b) {
  int t = blockIdx.x * 256 + threadIdx.x;
  const float* W; unsigned short* F; int KB;
  if (t < 4096) { W = W1a; F = F1a; KB = 8; }
  else if (t < 6144) { W = W1b; F = F1b; KB = 4; t -= 4096; }
  else if (t < 10240) { W = W2a; F = F2a; KB = 8; t -= 6144; }
  else if (t < 12288) { W = W2b; F = F2b; KB = 4; t -= 10240; }
  else return;
  int lane = t & 63;
  int frag = t >> 6;
  int nt = frag / KB;
  int kb = frag - nt * KB;
  int k = kb * 32 + (lane >> 4) * 8;
  int n = nt * 16 + (lane & 15);
  unsigned short v[8];
  #pragma unroll
  for (int j = 0; j < 8; ++j) v[j] = f2bf(W[(long long)(k + j) * 128 + n]);
  unsigned short* o = F + ((long long)frag * 64 + lane) * 8;
  *reinterpret_cast<int4*>(o) = *reinterpret_cast<int4*>(v);
}

// fp32 -> packed bf16 pairs (for word_emb)
__global__ __launch_bounds__(256) void conv_bf16_kernel(
    const float* __restrict__ in, unsigned* __restrict__ out, int npairs) {
  int t = blockIdx.x * 256 + threadIdx.x;
  if (t >= npairs) return;
  float2 v = reinterpret_cast<const float2*>(in)[t];
  out[t] = (unsigned)f2bf(v.x) | ((unsigned)f2bf(v.y) << 16);
}

// ---------------------------------------------------------------------------
// MFMA GEMM, fp32 A (layer 1, K=256): Y bf16 = relu(X@W+b)
// ---------------------------------------------------------------------------
template <int K>
__global__ __launch_bounds__(256) void gemm_mfma_f32a(
    const float* __restrict__ X, const unsigned short* __restrict__ Wf,
    const float* __restrict__ bias, unsigned short* __restrict__ Y, int N) {
  constexpr int KB = K / 32;
  const int lane = threadIdx.x & 63;
  const int wave = threadIdx.x >> 6;
  const int m_base = blockIdx.x * 64 + wave * 16;

  int arow = m_base + (lane & 15);
  if (arow >= N) arow = N - 1;
  const float* aptr = X + (long long)arow * K + (lane >> 4) * 8;

  float4v acc[8];
  #pragma unroll
  for (int nt = 0; nt < 8; ++nt) acc[nt] = (float4v)(0.f);

  #pragma unroll
  for (int kb = 0; kb < KB; ++kb) {
    float4 a0 = *reinterpret_cast<const float4*>(aptr + kb * 32);
    float4 a1 = *reinterpret_cast<const float4*>(aptr + kb * 32 + 4);
    unsigned short u[8];
    u[0] = f2bf(a0.x); u[1] = f2bf(a0.y); u[2] = f2bf(a0.z); u[3] = f2bf(a0.w);
    u[4] = f2bf(a1.x); u[5] = f2bf(a1.y); u[6] = f2bf(a1.z); u[7] = f2bf(a1.w);
    short8 afrag = *reinterpret_cast<short8*>(u);
    #pragma unroll
    for (int nt = 0; nt < 8; ++nt) {
      short8 bfrag = *reinterpret_cast<const short8*>(
          Wf + ((long long)(nt * KB + kb) * 64 + lane) * 8);
      acc[nt] = __builtin_amdgcn_mfma_f32_16x16x32_bf16(afrag, bfrag, acc[nt], 0, 0, 0);
    }
  }

  const int col = lane & 15;
  const int rbase = (lane >> 4) * 4;
  #pragma unroll
  for (int nt = 0; nt < 8; ++nt) {
    int n = nt * 16 + col;
    float b = bias[n];
    #pragma unroll
    for (int r = 0; r < 4; ++r) {
      int grow = m_base + rbase + r;
      if (grow < N) Y[(long long)grow * 128 + n] = f2bf(fmaxf(acc[nt][r] + b, 0.f));
    }
  }
}

// ---------------------------------------------------------------------------
// MFMA GEMM, bf16 A (layer 2, K=128): Y bf16 = relu(X@W+b)
// ---------------------------------------------------------------------------
template <int K>
__global__ __launch_bounds__(256) void gemm_mfma_bf16a(
    const unsigned short* __restrict__ X, const unsigned short* __restrict__ Wf,
    const float* __restrict__ bias, unsigned short* __restrict__ Y, int N) {
  constexpr int KB = K / 32;
  const int lane = threadIdx.x & 63;
  const int wave = threadIdx.x >> 6;
  const int m_base = blockIdx.x * 64 + wave * 16;

  int arow = m_base + (lane & 15);
  if (arow >= N) arow = N - 1;
  const unsigned short* aptr = X + (long long)arow * K + (lane >> 4) * 8;

  float4v acc[8];
  #pragma unroll
  for (int nt = 0; nt < 8; ++nt) acc[nt] = (float4v)(0.f);

  #pragma unroll
  for (int kb = 0; kb < KB; ++kb) {
    short8 afrag = *reinterpret_cast<const short8*>(aptr + kb * 32);
    #pragma unroll
    for (int nt = 0; nt < 8; ++nt) {
      short8 bfrag = *reinterpret_cast<const short8*>(
          Wf + ((long long)(nt * KB + kb) * 64 + lane) * 8);
      acc[nt] = __builtin_amdgcn_mfma_f32_16x16x32_bf16(afrag, bfrag, acc[nt], 0, 0, 0);
    }
  }

  const int col = lane & 15;
  const int rbase = (lane >> 4) * 4;
  #pragma unroll
  for (int nt = 0; nt < 8; ++nt) {
    int n = nt * 16 + col;
    float b = bias[n];
    #pragma unroll
    for (int r = 0; r < 4; ++r) {
      int grow = m_base + rbase + r;
      if (grow < N) Y[(long long)grow * 128 + n] = f2bf(fmaxf(acc[nt][r] + b, 0.f));
    }
  }
}

// ---------------------------------------------------------------------------
// Row-level histogram (global atomics) + 3-phase scan -> row offsets.
// ---------------------------------------------------------------------------
__global__ __launch_bounds__(256) void hist_all_kernel(
    const int* __restrict__ d11, int E11, int* __restrict__ c11,
    const int* __restrict__ d22, int E22, int* __restrict__ c22,
    const int* __restrict__ d01, int E01, int* __restrict__ c01,
    const int* __restrict__ d02, int E02, int* __restrict__ c02) {
  int t = blockIdx.x * 256 + threadIdx.x;
  if (t < E11) { atomicAdd(&c11[d11[t]], 1); return; }
  t -= E11;
  if (t < E22) { atomicAdd(&c22[d22[t]], 1); return; }
  t -= E22;
  if (t < E01) { atomicAdd(&c01[d01[t]], 1); return; }
  t -= E01;
  if (t < E02) { atomicAdd(&c02[d02[t]], 1); }
}

__global__ __launch_bounds__(256) void scan_local_kernel(
    const int* __restrict__ c11, int* __restrict__ o11, int n11,
    const int* __restrict__ c22, int* __restrict__ o22, int n22,
    const int* __restrict__ c01, int* __restrict__ o01, int n01,
    const int* __restrict__ c02, int* __restrict__ o02, int n02,
    int nc11, int nc22, int nc01, int* __restrict__ chunkSums) {
  int b = blockIdx.x;
  const int* c; int* o; int n; int chunk;
  if (b < nc11) { c = c11; o = o11; n = n11; chunk = b; }
  else if (b < nc11 + nc22) { c = c22; o = o22; n = n22; chunk = b - nc11; }
  else if (b < nc11 + nc22 + nc01) { c = c01; o = o01; n = n01; chunk = b - nc11 - nc22; }
  else { c = c02; o = o02; n = n02; chunk = b - nc11 - nc22 - nc01; }
  int tid = threadIdx.x;
  int i0 = chunk * SCHUNK + tid * 16;
  int loc[16];
  int s = 0;
  #pragma unroll
  for (int k = 0; k < 16; ++k) {
    int i = i0 + k;
    int x = (i < n) ? c[i] : 0;
    loc[k] = s;
    s += x;
  }
  __shared__ int sh[256];
  sh[tid] = s;
  __syncthreads();
  #pragma unroll
  for (int off = 1; off < 256; off <<= 1) {
    int t = (tid >= off) ? sh[tid - off] : 0;
    __syncthreads();
    sh[tid] += t;
    __syncthreads();
  }
  int excl = sh[tid] - s;
  #pragma unroll
  for (int k = 0; k < 16; ++k) {
    int i = i0 + k;
    if (i < n) o[i] = excl + loc[k];
  }
  if (tid == 255) chunkSums[b] = sh[255];
}

__global__ __launch_bounds__(64) void scan_sums_kernel(
    const int* __restrict__ chunkSums, int* __restrict__ chunkOffs,
    int nc11, int nc22, int nc01, int tc) {
  __shared__ int sh[64];
  int tid = threadIdx.x;
  if (tid < tc) sh[tid] = chunkSums[tid];
  __syncthreads();
  if (tid == 0) {
    int carry = 0;
    for (int b = 0; b < tc; ++b) {
      if (b == 0 || b == nc11 || b == nc11 + nc22 || b == nc11 + nc22 + nc01)
        carry = 0;
      chunkOffs[b] = carry;
      carry += sh[b];
    }
  }
}

__global__ __launch_bounds__(256) void scan_add_kernel(
    int* __restrict__ o11, int n11, int* __restrict__ o22, int n22,
    int* __restrict__ o01, int n01, int* __restrict__ o02, int n02,
    int nc11, int nc22, int nc01, const int* __restrict__ chunkOffs) {
  int b = blockIdx.x;
  int* o; int n; int chunk;
  if (b < nc11) { o = o11; n = n11; chunk = b; }
  else if (b < nc11 + nc22) { o = o22; n = n22; chunk = b - nc11; }
  else if (b < nc11 + nc22 + nc01) { o = o01; n = n01; chunk = b - nc11 - nc22; }
  else { o = o02; n = n02; chunk = b - nc11 - nc22 - nc01; }
  int add = chunkOffs[b];
  int tid = threadIdx.x;
  int i0 = chunk * SCHUNK + tid * 16;
  #pragma unroll
  for (int k = 0; k < 16; ++k) {
    int i = i0 + k;
    if (i < n) o[i] += add;
  }
}

// ---------------------------------------------------------------------------
// Bucket cursor init: cur[bucket] = row_offs[firstRow(bucket)]
// ---------------------------------------------------------------------------
__global__ __launch_bounds__(256) void bucket_cur_init(All4 A, int* __restrict__ cur,
                                                       int totb) {
  int i = blockIdx.x * 256 + threadIdx.x;
  if (i >= totb) return;
  int si = 3;
  if (i < A.s[1].cntBase) si = 0;
  else if (i < A.s[2].cntBase) si = 1;
  else if (i < A.s[3].cntBase) si = 2;
  const SetFull& d = A.s[si];
  int j = i - d.cntBase;
  cur[i] = d.offs[j << d.shift];
}

// ---------------------------------------------------------------------------
// Bucket binning: LDS hist -> block-aggregated reservation -> packed write.
// ---------------------------------------------------------------------------
__global__ __launch_bounds__(256) void bin_all_kernel(All4 A, int* __restrict__ cur) {
  int b = blockIdx.x;
  int si = 3;
  if (b < A.s[1].blkBase) si = 0;
  else if (b < A.s[2].blkBase) si = 1;
  else if (b < A.s[3].blkBase) si = 2;
  SetFull d = A.s[si];
  __shared__ int hc[1024];
  __shared__ int hb[1024];
  int tid = threadIdx.x;
  for (int i = tid; i < 1024; i += 256) hc[i] = 0;
  __syncthreads();
  int e0 = (b - d.blkBase) * EPB;
  int e1 = min(e0 + EPB, d.E);
  for (int e = e0 + tid; e < e1; e += 256)
    atomicAdd(&hc[d.dst[e] >> d.shift], 1);
  __syncthreads();
  for (int i = tid; i < d.nb; i += 256) {
    int c = hc[i];
    if (c) hb[i] = atomicAdd(&cur[d.cntBase + i], c);
    hc[i] = 0;
  }
  __syncthreads();
  int mask = (1 << d.shift) - 1;
  for (int e = e0 + tid; e < e1; e += 256) {
    int dstv = d.dst[e];
    int bkt = dstv >> d.shift;
    int pos = atomicAdd(&hc[bkt], 1);
    d.pkt[hb[bkt] + pos] = make_int2(((dstv & mask) << 16) | d.src[e],
                                     __float_as_int(d.w[e]));
  }
}

// ---------------------------------------------------------------------------
// Per-bucket LDS counting sort: pkt (bucket-binned) -> pkf (row-ordered).
// ---------------------------------------------------------------------------
__global__ __launch_bounds__(256) void sort_kernel(All4 A) {
  int b = blockIdx.x;
  int si = 3;
  if (b < A.s[1].cntBase) si = 0;
  else if (b < A.s[2].cntBase) si = 1;
  else if (b < A.s[3].cntBase) si = 2;
  SetFull d = A.s[si];
  int j = b - d.cntBase;
  int R = 1 << d.shift;
  int rb = j << d.shift;
  int rend = min(rb + R, d.N);
  __shared__ int rowCur[64];
  __shared__ int2 buf[SORT_CAP];
  int tid = threadIdx.x;
  int bucketStart = d.offs[rb];
  if (tid < rend - rb) rowCur[tid] = d.offs[rb + tid] - bucketStart;
  __syncthreads();
  int cnt = d.offs[rend] - bucketStart;
  if (cnt > SORT_CAP) cnt = SORT_CAP;  // statistically unreachable
  for (int t = tid; t < cnt; t += 256) {
    int2 rec = d.pkt[bucketStart + t];
    int dl = ((unsigned)rec.x) >> 16;
    int pos = atomicAdd(&rowCur[dl], 1);
    buf[pos] = rec;
  }
  __syncthreads();
  for (int t = tid; t < cnt; t += 256) d.pkf[bucketStart + t] = buf[t];
}

// ---------------------------------------------------------------------------
// Per-row register pull (bf16 gather), h11+h22 fused; 4x unrolled for MLP.
// ---------------------------------------------------------------------------
__global__ __launch_bounds__(256) void pull_h_kernel(
    const int* __restrict__ off1, const int2* __restrict__ pk1,
    const unsigned* __restrict__ X1, unsigned* __restrict__ Y1, int N1,
    const int* __restrict__ off2, const int2* __restrict__ pk2,
    const unsigned* __restrict__ X2, unsigned* __restrict__ Y2, int N2) {
  int row = blockIdx.x * 4 + (threadIdx.x >> 6);
  int lane = threadIdx.x & 63;
  const int* off; const int2* pk; const unsigned* X; unsigned* Y;
  if (row < N1) { off = off1; pk = pk1; X = X1; Y = Y1; }
  else {
    row -= N1;
    if (row >= N2) return;
    off = off2; pk = pk2; X = X2; Y = Y2;
  }
  int beg = off[row], end = off[row + 1];
  float ax0 = 0.f, ay0 = 0.f, ax1 = 0.f, ay1 = 0.f;
  int j = beg;
  for (; j + 3 < end; j += 4) {
    int2 p0 = pk[j];
    int2 p1 = pk[j + 1];
    int2 p2 = pk[j + 2];
    int2 p3 = pk[j + 3];
    unsigned v0 = X[((p0.x & 0xffff) << 6) + lane];
    unsigned v1 = X[((p1.x & 0xffff) << 6) + lane];
    unsigned v2 = X[((p2.x & 0xffff) << 6) + lane];
    unsigned v3 = X[((p3.x & 0xffff) << 6) + lane];
    float w0 = __int_as_float(p0.y);
    float w1 = __int_as_float(p1.y);
    float w2 = __int_as_float(p2.y);
    float w3 = __int_as_float(p3.y);
    ax0 += w0 * bf2f(v0 & 0xffff) + w1 * bf2f(v1 & 0xffff);
    ay0 += w0 * bf2f(v0 >> 16) + w1 * bf2f(v1 >> 16);
    ax1 += w2 * bf2f(v2 & 0xffff) + w3 * bf2f(v3 & 0xffff);
    ay1 += w2 * bf2f(v2 >> 16) + w3 * bf2f(v3 >> 16);
  }
  for (; j < end; ++j) {
    int2 p0 = pk[j];
    unsigned v0 = X[((p0.x & 0xffff) << 6) + lane];
    float w0 = __int_as_float(p0.y);
    ax0 += w0 * bf2f(v0 & 0xffff);
    ay0 += w0 * bf2f(v0 >> 16);
  }
  float ax = ax0 + ax1, ay = ay0 + ay1;
  Y[(row << 6) + lane] = (unsigned)f2bf(ax) | ((unsigned)f2bf(ay) << 16);
}

__device__ __forceinline__ float wave_sum64(float s) {
  #pragma unroll
  for (int off = 32; off; off >>= 1) s += __shfl_xor(s, off);
  return s;
}

// doc2: e01 rows; acc l2_1 & l1_1 (bf16); l2norm; out cols [0,128). 2x unroll.
__global__ __launch_bounds__(256) void doc2_kernel(
    const int* __restrict__ offs, const int2* __restrict__ pk,
    const unsigned* __restrict__ Xa, const unsigned* __restrict__ Xb,
    float* __restrict__ out, int N0) {
  int row = blockIdx.x * 4 + (threadIdx.x >> 6);
  int lane = threadIdx.x & 63;
  if (row >= N0) return;
  int beg = offs[row], end = offs[row + 1];
  float axx0 = 0.f, axy0 = 0.f, bxx0 = 0.f, bxy0 = 0.f;
  float axx1 = 0.f, axy1 = 0.f, bxx1 = 0.f, bxy1 = 0.f;
  int j = beg;
  for (; j + 1 < end; j += 2) {
    int2 p0 = pk[j];
    int2 p1 = pk[j + 1];
    int s0 = (p0.x & 0xffff) << 6;
    int s1 = (p1.x & 0xffff) << 6;
    unsigned va0 = Xa[s0 + lane];
    unsigned vb0 = Xb[s0 + lane];
    unsigned va1 = Xa[s1 + lane];
    unsigned vb1 = Xb[s1 + lane];
    float w0 = __int_as_float(p0.y);
    float w1 = __int_as_float(p1.y);
    axx0 += w0 * bf2f(va0 & 0xffff); axy0 += w0 * bf2f(va0 >> 16);
    bxx0 += w0 * bf2f(vb0 & 0xffff); bxy0 += w0 * bf2f(vb0 >> 16);
    axx1 += w1 * bf2f(va1 & 0xffff); axy1 += w1 * bf2f(va1 >> 16);
    bxx1 += w1 * bf2f(vb1 & 0xffff); bxy1 += w1 * bf2f(vb1 >> 16);
  }
  if (j < end) {
    int2 p0 = pk[j];
    int s0 = (p0.x & 0xffff) << 6;
    unsigned va0 = Xa[s0 + lane];
    unsigned vb0 = Xb[s0 + lane];
    float w0 = __int_as_float(p0.y);
    axx0 += w0 * bf2f(va0 & 0xffff); axy0 += w0 * bf2f(va0 >> 16);
    bxx0 += w0 * bf2f(vb0 & 0xffff); bxy0 += w0 * bf2f(vb0 >> 16);
  }
  float axx = axx0 + axx1, axy = axy0 + axy1;
  float bxx = bxx0 + bxx1, bxy = bxy0 + bxy1;
  const long long DOC = (long long)N0 * 384;
  float sa = wave_sum64(axx * axx + axy * axy);
  float inva = 1.0f / (sqrtf(sa) + 1e-9f);
  ((float2*)(out + (long long)row * 384))[lane] = make_float2(axx * inva, axy * inva);
  float sb = wave_sum64(bxx * bxx + bxy * bxy);
  float invb = 1.0f / (sqrtf(sb) + 1e-9f);
  ((float2*)(out + DOC + (long long)row * 384))[lane] = make_float2(bxx * invb, bxy * invb);
}

// doc3: e02 rows; acc l2_2, l1_2, wem (bf16); l2norm 256-dim; 2x unroll.
__global__ __launch_bounds__(256) void doc3_kernel(
    const int* __restrict__ offs, const int2* __restrict__ pk,
    const unsigned* __restrict__ Xa, const unsigned* __restrict__ Xb,
    const unsigned* __restrict__ Xw, float* __restrict__ out, int N0) {
  int row = blockIdx.x * 4 + (threadIdx.x >> 6);
  int lane = threadIdx.x & 63;
  if (row >= N0) return;
  int beg = offs[row], end = offs[row + 1];
  float axx0 = 0.f, axy0 = 0.f, bxx0 = 0.f, bxy0 = 0.f, wxx0 = 0.f, wxy0 = 0.f;
  float axx1 = 0.f, axy1 = 0.f, bxx1 = 0.f, bxy1 = 0.f, wxx1 = 0.f, wxy1 = 0.f;
  int j = beg;
  for (; j + 1 < end; j += 2) {
    int2 p0 = pk[j];
    int2 p1 = pk[j + 1];
    int s0 = (p0.x & 0xffff) << 6;
    int s1 = (p1.x & 0xffff) << 6;
    unsigned va0 = Xa[s0 + lane];
    unsigned vb0 = Xb[s0 + lane];
    unsigned vw0 = Xw[s0 + lane];
    unsigned va1 = Xa[s1 + lane];
    unsigned vb1 = Xb[s1 + lane];
    unsigned vw1 = Xw[s1 + lane];
    float w0 = __int_as_float(p0.y);
    float w1 = __int_as_float(p1.y);
    axx0 += w0 * bf2f(va0 & 0xffff); axy0 += w0 * bf2f(va0 >> 16);
    bxx0 += w0 * bf2f(vb0 & 0xffff); bxy0 += w0 * bf2f(vb0 >> 16);
    wxx0 += w0 * bf2f(vw0 & 0xffff); wxy0 += w0 * bf2f(vw0 >> 16);
    axx1 += w1 * bf2f(va1 & 0xffff); axy1 += w1 * bf2f(va1 >> 16);
    bxx1 += w1 * bf2f(vb1 & 0xffff); bxy1 += w1 * bf2f(vb1 >> 16);
    wxx1 += w1 * bf2f(vw1 & 0xffff); wxy1 += w1 * bf2f(vw1 >> 16);
  }
  if (j < end) {
    int2 p0 = pk[j];
    int s0 = (p0.x & 0xffff) << 6;
    unsigned va0 = Xa[s0 + lane];
    unsigned vb0 = Xb[s0 + lane];
    unsigned vw0 = Xw[s0 + lane];
    float w0 = __int_as_float(p0.y);
    axx0 += w0 * bf2f(va0 & 0xffff); axy0 += w0 * bf2f(va0 >> 16);
    bxx0 += w0 * bf2f(vb0 & 0xffff); bxy0 += w0 * bf2f(vb0 >> 16);
    wxx0 += w0 * bf2f(vw0 & 0xffff); wxy0 += w0 * bf2f(vw0 >> 16);
  }
  float axx = axx0 + axx1, axy = axy0 + axy1;
  float bxx = bxx0 + bxx1, bxy = bxy0 + bxy1;
  float wxx = wxx0 + wxx1, wxy = wxy0 + wxy1;
  const long long DOC = (long long)N0 * 384;
  float swp = wxx * wxx + wxy * wxy;
  float sa = wave_sum64(axx * axx + axy * axy + swp);
  float inva = 1.0f / (sqrtf(sa) + 1e-9f);
  float* o0 = out + (long long)row * 384 + 128;
  ((float2*)o0)[lane] = make_float2(axx * inva, axy * inva);
  ((float2*)(o0 + 128))[lane] = make_float2(wxx * inva, wxy * inva);
  float sb = wave_sum64(bxx * bxx + bxy * bxy + swp);
  float invb = 1.0f / (sqrtf(sb) + 1e-9f);
  float* o1 = out + DOC + (long long)row * 384 + 128;
  ((float2*)o1)[lane] = make_float2(bxx * invb, bxy * invb);
  ((float2*)(o1 + 128))[lane] = make_float2(wxx * invb, wxy * invb);
}

// ---------------------------------------------------------------------------
extern "C" void kernel_launch(void* const* d_in, const int* in_sizes, int n_in,
                              void* d_out, int out_size, void* d_ws,
                              size_t ws_size, hipStream_t stream) {
  const float* x1  = (const float*)d_in[0];
  const float* x2  = (const float*)d_in[1];
  const float* wem = (const float*)d_in[2];
  const float* W1a = (const float*)d_in[3];
  const float* b1a = (const float*)d_in[4];
  const float* W1b = (const float*)d_in[5];
  const float* b1b = (const float*)d_in[6];
  const float* W2a = (const float*)d_in[7];
  const float* b2a = (const float*)d_in[8];
  const float* W2b = (const float*)d_in[9];
  const float* b2b = (const float*)d_in[10];
  const int*   e11s = (const int*)d_in[11];
  const int*   e11d = (const int*)d_in[12];
  const float* e11w = (const float*)d_in[13];
  const int*   e22s = (const int*)d_in[14];
  const int*   e22d = (const int*)d_in[15];
  const float* e22w = (const float*)d_in[16];
  const int*   e01s = (const int*)d_in[17];
  const int*   e01d = (const int*)d_in[18];
  const float* e01w = (const float*)d_in[19];
  const int*   e02s = (const int*)d_in[20];
  const int*   e02d = (const int*)d_in[21];
  const float* e02w = (const float*)d_in[22];

  const int N0 = 10000;
  const int N1 = in_sizes[0] / 256;
  const int N2 = in_sizes[1] / 256;
  const int E11 = in_sizes[11];
  const int E22 = in_sizes[14];
  const int E01 = in_sizes[17];
  const int E02 = in_sizes[20];

  float* out = (float*)d_out;

  // ---- workspace ----
  char* base = (char*)d_ws;
  auto alloc = [&](size_t bytes) -> void* {
    void* r = (void*)base;
    base += (bytes + 255) & ~(size_t)255;
    return r;
  };
  // bf16 feature matrices (packed as unsigned pairs, 64 dwords/row)
  unsigned* l1_1 = (unsigned*)alloc((size_t)N1 * 64 * 4);
  unsigned* l1_2 = (unsigned*)alloc((size_t)N2 * 64 * 4);
  unsigned* l2_1 = (unsigned*)alloc((size_t)N1 * 64 * 4);
  unsigned* l2_2 = (unsigned*)alloc((size_t)N2 * 64 * 4);
  unsigned* h11  = (unsigned*)alloc((size_t)N1 * 64 * 4);
  unsigned* h22  = (unsigned*)alloc((size_t)N2 * 64 * 4);
  unsigned* wemb = (unsigned*)alloc((size_t)N2 * 64 * 4);

  unsigned short* F1a = (unsigned short*)alloc(8 * 8 * 64 * 8 * 2);
  unsigned short* F1b = (unsigned short*)alloc(8 * 4 * 64 * 8 * 2);
  unsigned short* F2a = (unsigned short*)alloc(8 * 8 * 64 * 8 * 2);
  unsigned short* F2b = (unsigned short*)alloc(8 * 4 * 64 * 8 * 2);

  const int n11 = N1 + 1, n22 = N2 + 1, n01 = N0 + 1, n02 = N0 + 1;
  const int P1 = (n11 + 63) & ~63;
  const int P2 = (n22 + 63) & ~63;
  const int P0 = (n01 + 63) & ~63;
  int* cnt_all = (int*)alloc((size_t)(P1 + P2 + P0 + P0) * 4);
  int* cnt11 = cnt_all;
  int* cnt22 = cnt_all + P1;
  int* cnt01 = cnt_all + P1 + P2;
  int* cnt02 = cnt_all + P1 + P2 + P0;
  int* off11 = (int*)alloc((size_t)P1 * 4);
  int* off22 = (int*)alloc((size_t)P2 * 4);
  int* off01 = (int*)alloc((size_t)P0 * 4);
  int* off02 = (int*)alloc((size_t)P0 * 4);
  int2* pkt11 = (int2*)alloc((size_t)E11 * 8);
  int2* pkt22 = (int2*)alloc((size_t)E22 * 8);
  int2* pkt01 = (int2*)alloc((size_t)E01 * 8);
  int2* pkt02 = (int2*)alloc((size_t)E02 * 8);
  int2* pkf11 = (int2*)alloc((size_t)E11 * 8);
  int2* pkf22 = (int2*)alloc((size_t)E22 * 8);
  int2* pkf01 = (int2*)alloc((size_t)E01 * 8);
  int2* pkf02 = (int2*)alloc((size_t)E02 * 8);
  int* bcur = (int*)alloc(2048 * 4);
  int* chunkSums = (int*)alloc(64 * 4);
  int* chunkOffs = (int*)alloc(64 * 4);

  // geometry
  const int nb11 = (N1 + 63) >> 6, nb22 = (N2 + 63) >> 6;
  const int nb01 = (N0 + 31) >> 5, nb02 = (N0 + 31) >> 5;
  const int TOTB = nb11 + nb22 + nb01 + nb02;
  const int B11 = (E11 + EPB - 1) / EPB, B22 = (E22 + EPB - 1) / EPB;
  const int B01 = (E01 + EPB - 1) / EPB, B02 = (E02 + EPB - 1) / EPB;
  const int BT = B11 + B22 + B01 + B02;
  const int Etot = E11 + E22 + E01 + E02;
  const int nc11 = (n11 + SCHUNK - 1) / SCHUNK;
  const int nc22 = (n22 + SCHUNK - 1) / SCHUNK;
  const int nc01 = (n01 + SCHUNK - 1) / SCHUNK;
  const int nc02 = (n02 + SCHUNK - 1) / SCHUNK;
  const int TC = nc11 + nc22 + nc01 + nc02;

  All4 A;
  A.s[0] = {e11s, e11d, e11w, off11, pkt11, pkf11, E11, N1, 6, nb11, 0, 0};
  A.s[1] = {e22s, e22d, e22w, off22, pkt22, pkf22, E22, N2, 6, nb22, nb11, B11};
  A.s[2] = {e01s, e01d, e01w, off01, pkt01, pkf01, E01, N0, 5, nb01,
            nb11 + nb22, B11 + B22};
  A.s[3] = {e02s, e02d, e02w, off02, pkt02, pkf02, E02, N0, 5, nb02,
            nb11 + nb22 + nb01, B11 + B22 + B01};

  // ---- row CSR offsets ----
  hipMemsetAsync(cnt_all, 0, (size_t)(P1 + P2 + P0 + P0) * 4, stream);
  hist_all_kernel<<<(Etot + 255) / 256, 256, 0, stream>>>(
      e11d, E11, cnt11, e22d, E22, cnt22, e01d, E01, cnt01, e02d, E02, cnt02);
  scan_local_kernel<<<TC, 256, 0, stream>>>(
      cnt11, off11, n11, cnt22, off22, n22, cnt01, off01, n01,
      cnt02, off02, n02, nc11, nc22, nc01, chunkSums);
  scan_sums_kernel<<<1, 64, 0, stream>>>(chunkSums, chunkOffs, nc11, nc22, nc01, TC);
  scan_add_kernel<<<TC, 256, 0, stream>>>(
      off11, n11, off22, n22, off01, n01, off02, n02, nc11, nc22, nc01, chunkOffs);

  // ---- bucket bin + per-bucket row sort ----
  bucket_cur_init<<<(TOTB + 255) / 256, 256, 0, stream>>>(A, bcur, TOTB);
  bin_all_kernel<<<BT, 256, 0, stream>>>(A, bcur);
  sort_kernel<<<TOTB, 256, 0, stream>>>(A);

  // ---- weight + wem conversion, layer-1 GEMMs ----
  conv_w_kernel<<<48, 256, 0, stream>>>(W1a, W1b, W2a, W2b, F1a, F1b, F2a, F2b);
  conv_bf16_kernel<<<(N2 * 64 + 255) / 256, 256, 0, stream>>>(wem, wemb, N2 * 64);
  gemm_mfma_f32a<256><<<(N1 + 63) / 64, 256, 0, stream>>>(x1, F1a, b1a,
                                                          (unsigned short*)l1_1, N1);
  gemm_mfma_f32a<256><<<(N2 + 63) / 64, 256, 0, stream>>>(x2, F2a, b2a,
                                                          (unsigned short*)l1_2, N2);

  // ---- layer 2: per-row pull then GEMM ----
  pull_h_kernel<<<(N1 + N2 + 3) / 4, 256, 0, stream>>>(
      off11, pkf11, l1_1, h11, N1, off22, pkf22, l1_2, h22, N2);
  gemm_mfma_bf16a<128><<<(N1 + 63) / 64, 256, 0, stream>>>(
      (const unsigned short*)h11, F1b, b1b, (unsigned short*)l2_1, N1);
  gemm_mfma_bf16a<128><<<(N2 + 63) / 64, 256, 0, stream>>>(
      (const unsigned short*)h22, F2b, b2b, (unsigned short*)l2_2, N2);

  // ---- doc aggregation + l2norm + concat ----
  doc2_kernel<<<(N0 + 3) / 4, 256, 0, stream>>>(off01, pkf01, l2_1, l1_1, out, N0);
  doc3_kernel<<<(N0 + 3) / 4, 256, 0, stream>>>(off02, pkf02, l2_2, l1_2, wemb, out, N0);
}